// Round 11
// baseline (106.064 us; speedup 1.0000x reference)
//
#include <hip/hip_runtime.h>
#include <math.h>

// Problem constants (fixed by the reference)
#define NN   5000
#define BB   4
#define SEQ  128
#define OUTC 128
#define EE   80000
#define KTOT 384   // [X | Txo | Txi] logical K; GEMM order: Txo,Txi (LDS) then X
#define CTOT 256   // interleaved: col cc = 2*o + gate (gate 0=Z, 1=H)
#define MTOT (BB * NN)   // 20000
#define MPAD 20096       // 314 * 64
#define CAP  64          // bucket capacity; Binom(80000,1/5000) max ~40 << 64
#define EBLK 313         // ceil(EE/256)
#define FBLK 384         // CTOT*KTOT/256 weight-fold blocks
#define XBLK 1250        // x->bf16 convert blocks

typedef __attribute__((ext_vector_type(8))) short bf16x8;
typedef __attribute__((ext_vector_type(4))) float f32x4;

__device__ inline unsigned short f2bf(float f) {   // RNE float->bf16
    union { float f; unsigned u; } a; a.f = f;
    unsigned r = a.u + 0x7FFF + ((a.u >> 16) & 1);
    return (unsigned short)(r >> 16);
}

// ---------------------------------------------------------------------------
// Zero deg/cnt region: 20000 floats.
// ---------------------------------------------------------------------------
__global__ __launch_bounds__(256) void k_zero(float* __restrict__ z) {
    int i = blockIdx.x * blockDim.x + threadIdx.x;
    if (i < 5000) {
        f32x4 zz = {0.f, 0.f, 0.f, 0.f};
        *(f32x4*)&z[i * 4] = zz;
    }
}

// ---------------------------------------------------------------------------
// One launch, three block roles (block-uniform branch):
//  [0,EBLK): edge pass — weighted degrees (atomic) + fixed-stride buckets.
//  [EBLK,EBLK+FBLK): weight fold WT[cc][k] bf16 (cc=2o+gate) + bias.
//  [EBLK+FBLK,..+XBLK): x -> bf16 copy (xb16), 8 elems/thread.
// ---------------------------------------------------------------------------
__global__ __launch_bounds__(256) void k_bucket_fold(
        const int* __restrict__ ei, const float* __restrict__ ew,
        const float* __restrict__ x,
        const float* __restrict__ Wz, const float* __restrict__ bz,
        const float* __restrict__ Wh, const float* __restrict__ bh,
        float* deg_out, float* deg_in,
        unsigned* cnt_in, unsigned* cnt_out,
        int2* __restrict__ bin, int2* __restrict__ bout,
        unsigned short* __restrict__ WT, float* __restrict__ bcat2,
        unsigned short* __restrict__ xb16) {
    int bid = blockIdx.x;
    if (bid < EBLK) {
        int e = bid * 256 + threadIdx.x;
        if (e >= EE) return;
        int s = ei[e], d = ei[EE + e];
        float w = ew[e];
        atomicAdd(&deg_out[s], w);
        atomicAdd(&deg_in[d], w);
        unsigned p = atomicAdd(&cnt_in[d], 1u);
        if (p < CAP) bin[((size_t)d << 6) + p] = make_int2(s, __float_as_int(w));
        unsigned q = atomicAdd(&cnt_out[s], 1u);
        if (q < CAP) bout[((size_t)s << 6) + q] = make_int2(d, __float_as_int(w));
    } else if (bid < EBLK + FBLK) {
        int i = (bid - EBLK) * 256 + threadIdx.x;   // [0, CTOT*KTOT)
        if (i < CTOT) bcat2[i] = (i & 1) ? bh[i >> 1] : bz[i >> 1];
        int cc = i / KTOT, k = i % KTOT;
        int gate = cc & 1, o = cc >> 1;
        const float* W = gate ? Wh : Wz;
        float v;
        if (k < 128)      v = W[(size_t)k * 128 + o] + W[(size_t)(512 + k) * 128 + o];
        else if (k < 256) v = W[(size_t)(256 + (k - 128)) * 128 + o];
        else              v = W[(size_t)(768 + (k - 256)) * 128 + o];
        WT[(size_t)cc * KTOT + k] = f2bf(v);
    } else {
        int j = (bid - EBLK - FBLK) * 256 + threadIdx.x;   // [0, 320000)
        if (j < (BB * NN * SEQ) / 8) {
            const float4* xp = (const float4*)x;
            float4 v0 = xp[(size_t)j * 2], v1 = xp[(size_t)j * 2 + 1];
            uint4 pk;
            pk.x = (unsigned)f2bf(v0.x) | ((unsigned)f2bf(v0.y) << 16);
            pk.y = (unsigned)f2bf(v0.z) | ((unsigned)f2bf(v0.w) << 16);
            pk.z = (unsigned)f2bf(v1.x) | ((unsigned)f2bf(v1.y) << 16);
            pk.w = (unsigned)f2bf(v1.z) | ((unsigned)f2bf(v1.w) << 16);
            ((uint4*)xb16)[j] = pk;
        }
    }
}

// ---------------------------------------------------------------------------
// FUSED diffuse + GEMM + epilogue. 314 blocks x 512 thr (8 waves), BM=64,
// BN=256 (full C width -> block's GEMM reads ONLY its own 64 rows: no
// cross-block dep, no global Tx buffer, one __syncthreads).
// Phase A: 64 rows x 2 lists = 128 units, unit u -> wave u%8; gather with
// 4-row-slot scheme; h==0 lanes write 16B into LDS Tx in MFMA-frag layout:
// frag(rb,j) at (rb*8+j)*1024 B, elem (rl,kk8): rl*16 + kk8*256 B
// (j = (list?4:0)+(q>>2), kk8 = q&3). Read side: lane l reads frag + l*16.
// Phase B: K-loop ks=0..11: ks<8 A from LDS Tx (k=128+32ks), ks>=8 A from
// xb16 global per-lane rows (k=32(ks-8)); B from WT global (L2-hot).
// All register-loaded, 1-step prefetch, zero staging barriers.
// ---------------------------------------------------------------------------
#define ACC8(A, v, cf) {                                              \
    A[0] += (cf) * __uint_as_float((v).x << 16);                      \
    A[1] += (cf) * __uint_as_float((v).x & 0xFFFF0000u);              \
    A[2] += (cf) * __uint_as_float((v).y << 16);                      \
    A[3] += (cf) * __uint_as_float((v).y & 0xFFFF0000u);              \
    A[4] += (cf) * __uint_as_float((v).z << 16);                      \
    A[5] += (cf) * __uint_as_float((v).z & 0xFFFF0000u);              \
    A[6] += (cf) * __uint_as_float((v).w << 16);                      \
    A[7] += (cf) * __uint_as_float((v).w & 0xFFFF0000u); }

__global__ __launch_bounds__(512) void k_fused(
        const unsigned short* __restrict__ xb16,
        const float* __restrict__ deg_out, const float* __restrict__ deg_in,
        const unsigned* __restrict__ cnt_in, const unsigned* __restrict__ cnt_out,
        const int2* __restrict__ bin, const int2* __restrict__ bout,
        const unsigned short* __restrict__ WT, const float* __restrict__ bcat2,
        float* __restrict__ out) {
    __shared__ unsigned short Tx[16384];        // 32 KB: 32 frags x 1024 B
    __shared__ int2 sb[8][CAP + 4];
    int t = threadIdx.x, w = t >> 6, l = t & 63;
    int n0 = blockIdx.x * 64;

    // ---------------- Phase A: diffuse own 64 rows into LDS Tx ----------
    {
        int h = l >> 4, q = l & 15;
#pragma unroll 2
        for (int it = 0; it < 16; ++it) {
            int u = w + it * 8;                 // [0,128)
            int row_local = u >> 1, list = u & 1;
            int r = n0 + row_local;
            int valid = (r < MTOT);
            int b = (r >= 15000) ? 3 : (r >= 10000) ? 2 : (r >= 5000) ? 1 : 0;
            int n = valid ? (r - b * NN) : 0;
            if (!valid) b = 0;
            const unsigned short* xb = xb16 + (size_t)b * NN * SEQ;
            const int2* bkt = list ? bout : bin;
            const float* dga = list ? deg_in : deg_out;
            int m = valid ? (int)min((list ? cnt_out : cnt_in)[n], (unsigned)CAP) : 0;
            if (l < m) {
                int2 e = bkt[((size_t)n << 6) + l];
                float dg = dga[e.x];
                float cf = dg > 0.f ? __int_as_float(e.y) / dg : 0.f;
                sb[w][l] = make_int2(e.x, __float_as_int(cf));
            } else if (l < ((m + 3) & ~3)) {
                sb[w][l] = make_int2(0, 0);     // pad to multiple of 4
            }
            int me = (m + 3) & ~3;

            float a[8] = {0.f, 0.f, 0.f, 0.f, 0.f, 0.f, 0.f, 0.f};
            int j = 0;
            for (; j + 7 < me; j += 8) {        // 2 loads in flight
                int2 e0 = sb[w][j + h], e1 = sb[w][j + 4 + h];
                uint4 v0 = *(const uint4*)&xb[(size_t)e0.x * SEQ + 8 * q];
                uint4 v1 = *(const uint4*)&xb[(size_t)e1.x * SEQ + 8 * q];
                float c0 = __int_as_float(e0.y), c1 = __int_as_float(e1.y);
                ACC8(a, v0, c0);
                ACC8(a, v1, c1);
            }
            for (; j < me; j += 4) {
                int2 e0 = sb[w][j + h];
                uint4 v0 = *(const uint4*)&xb[(size_t)e0.x * SEQ + 8 * q];
                float c0 = __int_as_float(e0.y);
                ACC8(a, v0, c0);
            }
#pragma unroll
            for (int rr = 0; rr < 8; ++rr) {    // reduce 4 row-slots
                a[rr] += __shfl_xor(a[rr], 16);
                a[rr] += __shfl_xor(a[rr], 32);
            }
            if (h == 0) {                       // 16 lanes x 16 B = 128 cols
                int jf = (list ? 4 : 0) + (q >> 2);
                int rb = row_local >> 4, rl = row_local & 15;
                uint4 pk;
                pk.x = (unsigned)f2bf(a[0]) | ((unsigned)f2bf(a[1]) << 16);
                pk.y = (unsigned)f2bf(a[2]) | ((unsigned)f2bf(a[3]) << 16);
                pk.z = (unsigned)f2bf(a[4]) | ((unsigned)f2bf(a[5]) << 16);
                pk.w = (unsigned)f2bf(a[6]) | ((unsigned)f2bf(a[7]) << 16);
                *(uint4*)&Tx[(rb * 8 + jf) * 512 + rl * 8 + (q & 3) * 128] = pk;
            }
        }
    }
    __syncthreads();

    // ---------------- Phase B: GEMM 64x256xK384, register operands -------
    int lr = l & 15, lk = l >> 4;
    int wr = w >> 2, wc = w & 3;                // 2(M) x 4(N) wave grid
    f32x4 acc[2][4] = {};

    const unsigned short* wp[4];                // B rows: col cb*16+lr
#pragma unroll
    for (int jj = 0; jj < 4; ++jj)
        wp[jj] = WT + (size_t)((wc * 4 + jj) * 16 + lr) * KTOT + lk * 8;

    const unsigned short* xp[2];                // A-X rows for rb=wr*2+i
#pragma unroll
    for (int i = 0; i < 2; ++i) {
        int r = n0 + (wr * 2 + i) * 16 + lr;
        if (r >= MTOT) r = 0;                   // clamp (values unused)
        int b = (r >= 15000) ? 3 : (r >= 10000) ? 2 : (r >= 5000) ? 1 : 0;
        xp[i] = xb16 + ((size_t)b * NN + (r - b * NN)) * SEQ + lk * 8;
    }

    bf16x8 ar[2][2], br[2][4];
#define LOADK(buf, ks) {                                                          \
        if ((ks) < 8) {                                                           \
            _Pragma("unroll")                                                     \
            for (int i = 0; i < 2; ++i)                                           \
                ar[buf][i] = *(const bf16x8*)&Tx[((wr * 2 + i) * 8 + (ks)) * 512 + l * 8]; \
            _Pragma("unroll")                                                     \
            for (int jj = 0; jj < 4; ++jj)                                        \
                br[buf][jj] = *(const bf16x8*)(wp[jj] + 128 + 32 * (ks));         \
        } else {                                                                  \
            _Pragma("unroll")                                                     \
            for (int i = 0; i < 2; ++i)                                           \
                ar[buf][i] = *(const bf16x8*)(xp[i] + 32 * ((ks) - 8));           \
            _Pragma("unroll")                                                     \
            for (int jj = 0; jj < 4; ++jj)                                        \
                br[buf][jj] = *(const bf16x8*)(wp[jj] + 32 * ((ks) - 8));         \
        } }

    LOADK(0, 0);
#pragma unroll
    for (int ks = 0; ks < 12; ++ks) {
        if (ks + 1 < 12) LOADK((ks + 1) & 1, ks + 1);
#pragma unroll
        for (int i = 0; i < 2; ++i)
#pragma unroll
            for (int jj = 0; jj < 4; ++jj)
                acc[i][jj] = __builtin_amdgcn_mfma_f32_16x16x32_bf16(
                    ar[ks & 1][i], br[ks & 1][jj], acc[i][jj], 0, 0, 0);
    }
#undef LOADK

    // ---------------- Epilogue ------------------------------------------
    // row = n0 + wr*32 + i*16 + lk*4 + rr, col cc = wc*64 + jj*16 + lr
    int row_base = n0 + wr * 32;
    bool odd = (l & 1);
#pragma unroll
    for (int jj = 0; jj < 4; ++jj) {
        int cc = wc * 64 + jj * 16 + lr;
        float bias = bcat2[cc];
        int o = cc >> 1;
#pragma unroll
        for (int i = 0; i < 2; ++i) {
#pragma unroll
            for (int rr = 0; rr < 4; ++rr) {
                float v = acc[i][jj][rr] + bias;
                // even lane (v=z_pre): u = 1/(1+e^v)    = 1 - sigmoid(v)
                // odd  lane (v=h_pre): u = 1-2/(e^2v+1) = tanh(v)
                float ex = __expf(odd ? 2.f * v : v);
                float u = odd ? (1.f - 2.f / (ex + 1.f)) : (1.f / (1.f + ex));
                float g = __shfl_xor(u, 1);
                if (!odd) {
                    int row = row_base + i * 16 + lk * 4 + rr;
                    if (row < MTOT) out[(size_t)row * OUTC + o] = u * g;
                }
            }
        }
    }
}

// ---------------------------------------------------------------------------
extern "C" void kernel_launch(void* const* d_in, const int* in_sizes, int n_in,
                              void* d_out, int out_size, void* d_ws, size_t ws_size,
                              hipStream_t stream) {
    const float* x  = (const float*)d_in[0];
    const int*   ei = (const int*)d_in[1];
    const float* ew = (const float*)d_in[2];
    const float* Wz = (const float*)d_in[3];
    const float* bz = (const float*)d_in[4];
    // d_in[5]=Wr, d_in[6]=br dead (H0==0 -> Xc2==Xc, R unused)
    const float* Wh = (const float*)d_in[7];
    const float* bh = (const float*)d_in[8];

    float* ws = (float*)d_ws;
    float*    deg_out = ws + 0;                        // 5000
    float*    deg_in  = ws + 5000;                     // 5000
    unsigned* cnt_in  = (unsigned*)(ws + 10000);       // 5000
    unsigned* cnt_out = (unsigned*)(ws + 15000);       // 5000
    float*    bcat2   = ws + 20000;                    // 256
    unsigned short* WT = (unsigned short*)(ws + 20256);  // 256*384 bf16 (49152 fl)
    int2*     bin  = (int2*)(ws + 69408);              // 5000*64 int2 (640000 fl)
    int2*     bout = (int2*)(ws + 709408);             // 5000*64 int2 (640000 fl)
    unsigned short* xb16 = (unsigned short*)(ws + 1349408); // 2.56M bf16 (1.28M fl)

    k_zero<<<20, 256, 0, stream>>>(ws);
    k_bucket_fold<<<EBLK + FBLK + XBLK, 256, 0, stream>>>(
        ei, ew, x, Wz, bz, Wh, bh, deg_out, deg_in, cnt_in, cnt_out,
        bin, bout, WT, bcat2, xb16);
    k_fused<<<MPAD / 64, 512, 0, stream>>>(xb16, deg_out, deg_in, cnt_in, cnt_out,
                                           bin, bout, WT, bcat2, (float*)d_out);
}

// Round 12
// 68.796 us; speedup vs baseline: 1.5417x; 1.5417x over previous
//
#include <hip/hip_runtime.h>
#include <math.h>

// Problem constants (fixed by the reference)
#define NN   5000
#define BB   4
#define SEQ  128
#define OUTC 128
#define EE   80000
#define KTOT 384   // [X | Txo | Txi]
#define CTOT 256   // interleaved: col cc = 2*o + gate (gate 0=Z, 1=H)
#define MTOT (BB * NN)   // 20000
#define MPAD 20096       // 157 * 128
#define CAP  64          // bucket capacity; Binom(80000,1/5000) max ~40 << 64
#define EBLK 313         // ceil(EE/256)
#define FBLK 384         // CTOT*KTOT/256 weight-fold blocks

typedef __attribute__((ext_vector_type(8))) short bf16x8;
typedef __attribute__((ext_vector_type(4))) float f32x4;

__device__ inline unsigned short f2bf(float f) {   // RNE float->bf16
    union { float f; unsigned u; } a; a.f = f;
    unsigned r = a.u + 0x7FFF + ((a.u >> 16) & 1);
    return (unsigned short)(r >> 16);
}

// ---------------------------------------------------------------------------
// Zero cnt_in/cnt_out: 10000 uints.
// ---------------------------------------------------------------------------
__global__ __launch_bounds__(256) void k_zero(unsigned* __restrict__ z) {
    int i = blockIdx.x * blockDim.x + threadIdx.x;
    if (i < 2500) {
        uint4 zz = {0u, 0u, 0u, 0u};
        ((uint4*)z)[i] = zz;
    }
}

// ---------------------------------------------------------------------------
// Edge pass (cnt atomics + bucket stores ONLY — float deg atomics deleted;
// degrees are recomputed locally from buckets in k_norm) + weight fold.
// ---------------------------------------------------------------------------
__global__ __launch_bounds__(256) void k_bucket_fold(
        const int* __restrict__ ei, const float* __restrict__ ew,
        const float* __restrict__ Wz, const float* __restrict__ bz,
        const float* __restrict__ Wh, const float* __restrict__ bh,
        unsigned* cnt_in, unsigned* cnt_out,
        int2* __restrict__ bin, int2* __restrict__ bout,
        unsigned short* __restrict__ WT, float* __restrict__ bcat2) {
    int bid = blockIdx.x;
    if (bid < EBLK) {
        int e = bid * 256 + threadIdx.x;
        if (e >= EE) return;
        int s = ei[e], d = ei[EE + e];
        float w = ew[e];
        unsigned p = atomicAdd(&cnt_in[d], 1u);
        if (p < CAP) bin[((size_t)d << 6) + p] = make_int2(s, __float_as_int(w));
        unsigned q = atomicAdd(&cnt_out[s], 1u);
        if (q < CAP) bout[((size_t)s << 6) + q] = make_int2(d, __float_as_int(w));
    } else {
        int i = (bid - EBLK) * 256 + threadIdx.x;   // [0, CTOT*KTOT)
        if (i < CTOT) bcat2[i] = (i & 1) ? bh[i >> 1] : bz[i >> 1];
        int cc = i / KTOT, k = i % KTOT;
        int gate = cc & 1, o = cc >> 1;
        const float* W = gate ? Wh : Wz;
        float v;
        if (k < 128)      v = W[(size_t)k * 128 + o] + W[(size_t)(512 + k) * 128 + o];
        else if (k < 256) v = W[(size_t)(256 + (k - 128)) * 128 + o];
        else              v = W[(size_t)(768 + (k - 256)) * 128 + o];
        WT[(size_t)cc * KTOT + k] = f2bf(v);
    }
}

// ---------------------------------------------------------------------------
// Normalize: one wave per node. deg_out[n] = sum w over bout[n] (local
// shuffle reduce — no atomics, no random gather); deg_in[n] from bin[n].
// Writes 3 bf16 row-sets for all 4 batches: xb16 = x (plain, for GEMM X
// part), xn_o = x*dinv_out (gathered by in-lists), xn_i = x*dinv_in
// (gathered by out-lists). Lane l handles cols 2l, 2l+1.
// ---------------------------------------------------------------------------
__global__ __launch_bounds__(256) void k_norm(
        const float* __restrict__ x,
        const unsigned* __restrict__ cnt_in, const unsigned* __restrict__ cnt_out,
        const int2* __restrict__ bin, const int2* __restrict__ bout,
        unsigned short* __restrict__ xb16,
        unsigned short* __restrict__ xn_o, unsigned short* __restrict__ xn_i) {
    int wv = threadIdx.x >> 6, l = threadIdx.x & 63;
    int n = blockIdx.x * 4 + wv;
    if (n >= NN) return;
    int mi = (int)min(cnt_in[n], (unsigned)CAP);
    int mo = (int)min(cnt_out[n], (unsigned)CAP);
    float wi = 0.f, wo = 0.f;
    if (l < mi) wi = __int_as_float(bin[((size_t)n << 6) + l].y);
    if (l < mo) wo = __int_as_float(bout[((size_t)n << 6) + l].y);
#pragma unroll
    for (int s = 1; s < 64; s <<= 1) {
        wi += __shfl_xor(wi, s);
        wo += __shfl_xor(wo, s);
    }
    float dio = wo > 0.f ? 1.f / wo : 0.f;   // dinv_out[n]
    float dii = wi > 0.f ? 1.f / wi : 0.f;   // dinv_in[n]
#pragma unroll
    for (int b = 0; b < BB; ++b) {
        size_t off = ((size_t)b * NN + n) * SEQ + 2 * l;
        float2 xv = *(const float2*)&x[off];
        *(unsigned*)&xb16[off] = (unsigned)f2bf(xv.x) | ((unsigned)f2bf(xv.y) << 16);
        *(unsigned*)&xn_o[off] = (unsigned)f2bf(xv.x * dio) | ((unsigned)f2bf(xv.y * dio) << 16);
        *(unsigned*)&xn_i[off] = (unsigned)f2bf(xv.x * dii) | ((unsigned)f2bf(xv.y * dii) << 16);
    }
}

// ---------------------------------------------------------------------------
// Diffusion, one wave per (node, batch, list): 40000 waves. No deg lookup,
// no division: gathers from the pre-normalized array (in-list -> xn_o,
// out-list -> xn_i), coefficient is the raw edge weight. Lane l: slot
// h=l>>4 (row j+h), col group q=l&15 (8 bf16); one uint4 load = 4 rows x
// 128 cols per wave-instruction. Cross-slot reduce via shfl_xor(16/32).
// XCD swizzle: blockIdx&7 -> batch slot (L2 affinity).
// ---------------------------------------------------------------------------
#define ACC8(A, v, cf) {                                              \
    A[0] += (cf) * __uint_as_float((v).x << 16);                      \
    A[1] += (cf) * __uint_as_float((v).x & 0xFFFF0000u);              \
    A[2] += (cf) * __uint_as_float((v).y << 16);                      \
    A[3] += (cf) * __uint_as_float((v).y & 0xFFFF0000u);              \
    A[4] += (cf) * __uint_as_float((v).z << 16);                      \
    A[5] += (cf) * __uint_as_float((v).z & 0xFFFF0000u);              \
    A[6] += (cf) * __uint_as_float((v).w << 16);                      \
    A[7] += (cf) * __uint_as_float((v).w & 0xFFFF0000u); }

__global__ __launch_bounds__(256) void k_diffuse(
        const unsigned short* __restrict__ xn_o, const unsigned short* __restrict__ xn_i,
        const unsigned* __restrict__ cnt_in, const unsigned* __restrict__ cnt_out,
        const int2* __restrict__ bin, const int2* __restrict__ bout,
        unsigned short* __restrict__ Inb) {
    __shared__ int2 sb[4][CAP + 4];
    int bid = blockIdx.x;                 // [0, 10000)
    int slot = bid & 7, pos = bid >> 3;   // pos in [0, 1250)
    int b = slot >> 1, half = slot & 1;
    int wv = threadIdx.x >> 6;
    int unit = pos * 4 + wv;              // [0, 5000)
    int nl = unit >> 1;                   // node-local [0, 2500)
    int list = unit & 1;                  // 0: in-list (Txo), 1: out-list (Txi)
    int n = nl * 2 + half;
    int l = threadIdx.x & 63;
    int h = l >> 4, q = l & 15;
    const unsigned short* xs = (list ? xn_i : xn_o) + (size_t)b * NN * SEQ;

    const int2* bkt = list ? bout : bin;
    int m = (int)min((list ? cnt_out : cnt_in)[n], (unsigned)CAP);
    if (l < m) {
        sb[wv][l] = bkt[((size_t)n << 6) + l];      // (idx, w) raw
    } else if (l < ((m + 3) & ~3)) {
        sb[wv][l] = make_int2(0, 0);                // pad: w=0 -> no contrib
    }
    int me = (m + 3) & ~3;

    float a[8] = {0.f, 0.f, 0.f, 0.f, 0.f, 0.f, 0.f, 0.f};
    int j = 0;
    for (; j + 7 < me; j += 8) {   // 2 loads in flight
        int2 e0 = sb[wv][j + h], e1 = sb[wv][j + 4 + h];
        uint4 v0 = *(const uint4*)&xs[(size_t)e0.x * SEQ + 8 * q];
        uint4 v1 = *(const uint4*)&xs[(size_t)e1.x * SEQ + 8 * q];
        float c0 = __int_as_float(e0.y), c1 = __int_as_float(e1.y);
        ACC8(a, v0, c0);
        ACC8(a, v1, c1);
    }
    for (; j < me; j += 4) {
        int2 e0 = sb[wv][j + h];
        uint4 v0 = *(const uint4*)&xs[(size_t)e0.x * SEQ + 8 * q];
        float c0 = __int_as_float(e0.y);
        ACC8(a, v0, c0);
    }

    // reduce over the 4 row-slots (lanes l, l^16, l^32, l^48)
#pragma unroll
    for (int r = 0; r < 8; ++r) {
        a[r] += __shfl_xor(a[r], 16);
        a[r] += __shfl_xor(a[r], 32);
    }

    // h==0 lanes (16 x uint4 = 256 B) store this wave's 128-col half
    if (h == 0) {
        unsigned short* rw = Inb + (size_t)(b * NN + n) * 256 + (list ? 128 : 0);
        uint4 pk;
        pk.x = (unsigned)f2bf(a[0]) | ((unsigned)f2bf(a[1]) << 16);
        pk.y = (unsigned)f2bf(a[2]) | ((unsigned)f2bf(a[3]) << 16);
        pk.z = (unsigned)f2bf(a[4]) | ((unsigned)f2bf(a[5]) << 16);
        pk.w = (unsigned)f2bf(a[6]) | ((unsigned)f2bf(a[7]) << 16);
        *(uint4*)&rw[8 * q] = pk;
    }
}

// ---------------------------------------------------------------------------
// MFMA GEMM + fused epilogue (R8-proven). 8 waves/block (512 thr), wave-tile
// 64x32 -> 2512 waves. A: k<128 from xb16 (per-lane row ptr), k>=128 from
// Inb[r][256]. 3-buffer counted-vmcnt pipeline (steady-state vmcnt(2)).
// Epilogue: even lane 1/(1+e^z)=1-sigm, odd lane tanh; shfl_xor(1) combines.
// ---------------------------------------------------------------------------
__global__ __launch_bounds__(512) void k_mm(
        const unsigned short* __restrict__ xb16,
        const unsigned short* __restrict__ Inb, const unsigned short* __restrict__ WT,
        const float* __restrict__ bcat2, float* __restrict__ out) {
    __shared__ unsigned short lA[3][4096];  // [buf][frag f*512 + lane*8]
    __shared__ unsigned short lB[3][4096];
    int t = threadIdx.x, w = t >> 6, l = t & 63;
    int lr = l & 15, lk = l >> 4;
    int n0 = blockIdx.x * 128;
    int c0 = blockIdx.y * 128;
    int wr = w >> 2, wc = w & 3;
    f32x4 acc[4][2] = {};

    // per-lane source rows for this wave's staged fragment (f == w)
    int r = n0 + w * 16 + lr;
    int bidx = (r >= 15000) ? 3 : (r >= 10000) ? 2 : (r >= 5000) ? 1 : 0;
    const unsigned short* xrow = xb16 + ((size_t)bidx * NN + (r - bidx * NN)) * SEQ;
    const unsigned short* irow = Inb + (size_t)r * 256;
    const unsigned short* wrow = WT + (size_t)(c0 + w * 16 + lr) * KTOT;

#define STAGE(buf, k0)                                                            \
    {                                                                             \
        const unsigned short* sa = ((k0) < 128) ? (xrow + (k0) + lk * 8)          \
                                                : (irow + ((k0) - 128) + lk * 8); \
        __builtin_amdgcn_global_load_lds(                                         \
            (const __attribute__((address_space(1))) void*)sa,                    \
            (__attribute__((address_space(3))) void*)&lA[buf][w * 512], 16, 0, 0);\
        const unsigned short* sb = wrow + (k0) + lk * 8;                          \
        __builtin_amdgcn_global_load_lds(                                         \
            (const __attribute__((address_space(1))) void*)sb,                    \
            (__attribute__((address_space(3))) void*)&lB[buf][w * 512], 16, 0, 0);\
    }

    STAGE(0, 0);
    STAGE(1, 32);

#pragma unroll
    for (int ks = 0; ks < 12; ++ks) {
        if (ks < 11) asm volatile("s_waitcnt vmcnt(2)" ::: "memory");
        else         asm volatile("s_waitcnt vmcnt(0)" ::: "memory");
        __builtin_amdgcn_s_barrier();
        const int bf = ks % 3;
        bf16x8 a[4], bfr[2];
#pragma unroll
        for (int i = 0; i < 4; ++i) a[i] = *(const bf16x8*)&lA[bf][(wr * 4 + i) * 512 + l * 8];
#pragma unroll
        for (int jj = 0; jj < 2; ++jj) bfr[jj] = *(const bf16x8*)&lB[bf][(wc * 2 + jj) * 512 + l * 8];
#pragma unroll
        for (int i = 0; i < 4; ++i)
#pragma unroll
            for (int jj = 0; jj < 2; ++jj)
                acc[i][jj] = __builtin_amdgcn_mfma_f32_16x16x32_bf16(a[i], bfr[jj], acc[i][jj], 0, 0, 0);
        if (ks + 2 < 12) STAGE((ks + 2) % 3, (ks + 2) * 32);
    }
#undef STAGE

    // Epilogue: row = n0+wr*64+i*16+lk*4+rr, col cc = c0+wc*32+jj*16+lr
    int row_base = n0 + wr * 64;
    bool odd = (l & 1);
#pragma unroll
    for (int jj = 0; jj < 2; ++jj) {
        int cc = c0 + wc * 32 + jj * 16 + lr;
        float bias = bcat2[cc];
        int o = cc >> 1;
#pragma unroll
        for (int i = 0; i < 4; ++i) {
#pragma unroll
            for (int rr = 0; rr < 4; ++rr) {
                float v = acc[i][jj][rr] + bias;
                // even lane (v=z_pre): u = 1/(1+e^v)    = 1 - sigmoid(v)
                // odd  lane (v=h_pre): u = 1-2/(e^2v+1) = tanh(v)
                float ex = __expf(odd ? 2.f * v : v);
                float u = odd ? (1.f - 2.f / (ex + 1.f)) : (1.f / (1.f + ex));
                float g = __shfl_xor(u, 1);
                if (!odd) {
                    int row = row_base + i * 16 + lk * 4 + rr;
                    if (row < MTOT) out[(size_t)row * OUTC + o] = u * g;
                }
            }
        }
    }
}

// ---------------------------------------------------------------------------
extern "C" void kernel_launch(void* const* d_in, const int* in_sizes, int n_in,
                              void* d_out, int out_size, void* d_ws, size_t ws_size,
                              hipStream_t stream) {
    const float* x  = (const float*)d_in[0];
    const int*   ei = (const int*)d_in[1];
    const float* ew = (const float*)d_in[2];
    const float* Wz = (const float*)d_in[3];
    const float* bz = (const float*)d_in[4];
    // d_in[5]=Wr, d_in[6]=br dead (H0==0 -> Xc2==Xc, R unused)
    const float* Wh = (const float*)d_in[7];
    const float* bh = (const float*)d_in[8];

    float* ws = (float*)d_ws;
    unsigned* cnt_in  = (unsigned*)(ws + 0);           // 5000
    unsigned* cnt_out = (unsigned*)(ws + 5000);        // 5000
    float*    bcat2   = ws + 10000;                    // 256
    unsigned short* WT = (unsigned short*)(ws + 10256);  // 256*384 bf16 (49152 fl)
    int2*     bin  = (int2*)(ws + 59408);              // 5000*64 int2 (640000 fl)
    int2*     bout = (int2*)(ws + 699408);             // 5000*64 int2 (640000 fl)
    unsigned short* xb16 = (unsigned short*)(ws + 1339408); // 2.56M bf16 (1.28M fl)
    unsigned short* xn_o = (unsigned short*)(ws + 2619408); // 2.56M bf16
    unsigned short* xn_i = (unsigned short*)(ws + 3899408); // 2.56M bf16
    unsigned short* Inb  = (unsigned short*)(ws + 5179408); // MPAD*256 bf16

    k_zero<<<10, 256, 0, stream>>>((unsigned*)ws);
    k_bucket_fold<<<EBLK + FBLK, 256, 0, stream>>>(
        ei, ew, Wz, bz, Wh, bh, cnt_in, cnt_out, bin, bout, WT, bcat2);
    k_norm<<<1250, 256, 0, stream>>>(x, cnt_in, cnt_out, bin, bout, xb16, xn_o, xn_i);
    k_diffuse<<<2 * NN, 256, 0, stream>>>(xn_o, xn_i, cnt_in, cnt_out, bin, bout, Inb);
    dim3 g(MPAD / 128, 2);
    k_mm<<<g, 512, 0, stream>>>(xb16, Inb, WT, bcat2, (float*)d_out);
}

// Round 13
// 67.925 us; speedup vs baseline: 1.5615x; 1.0128x over previous
//
#include <hip/hip_runtime.h>
#include <math.h>

// Problem constants (fixed by the reference)
#define NN   5000
#define BB   4
#define SEQ  128
#define OUTC 128
#define EE   80000
#define KTOT 384   // [X | Txo | Txi]
#define CTOT 256   // interleaved: col cc = 2*o + gate (gate 0=Z, 1=H)
#define MTOT (BB * NN)   // 20000
#define MPAD 20096       // 157 * 128
#define CAP  64          // bucket capacity; Binom(80000,1/5000) max ~40 << 64
#define EBLK 313         // ceil(EE/256)
#define FBLK 384         // CTOT*KTOT/256 weight-fold blocks

typedef __attribute__((ext_vector_type(8))) short bf16x8;
typedef __attribute__((ext_vector_type(4))) float f32x4;

__device__ inline unsigned short f2bf(float f) {   // RNE float->bf16
    union { float f; unsigned u; } a; a.f = f;
    unsigned r = a.u + 0x7FFF + ((a.u >> 16) & 1);
    return (unsigned short)(r >> 16);
}

// ---------------------------------------------------------------------------
// Zero cnt_in/cnt_out: 10000 uints.
// ---------------------------------------------------------------------------
__global__ __launch_bounds__(256) void k_zero(unsigned* __restrict__ z) {
    int i = blockIdx.x * blockDim.x + threadIdx.x;
    if (i < 2500) {
        uint4 zz = {0u, 0u, 0u, 0u};
        ((uint4*)z)[i] = zz;
    }
}

// ---------------------------------------------------------------------------
// Edge pass (cnt atomics + bucket stores ONLY) + weight fold.
// ---------------------------------------------------------------------------
__global__ __launch_bounds__(256) void k_bucket_fold(
        const int* __restrict__ ei, const float* __restrict__ ew,
        const float* __restrict__ Wz, const float* __restrict__ bz,
        const float* __restrict__ Wh, const float* __restrict__ bh,
        unsigned* cnt_in, unsigned* cnt_out,
        int2* __restrict__ bin, int2* __restrict__ bout,
        unsigned short* __restrict__ WT, float* __restrict__ bcat2) {
    int bid = blockIdx.x;
    if (bid < EBLK) {
        int e = bid * 256 + threadIdx.x;
        if (e >= EE) return;
        int s = ei[e], d = ei[EE + e];
        float w = ew[e];
        unsigned p = atomicAdd(&cnt_in[d], 1u);
        if (p < CAP) bin[((size_t)d << 6) + p] = make_int2(s, __float_as_int(w));
        unsigned q = atomicAdd(&cnt_out[s], 1u);
        if (q < CAP) bout[((size_t)s << 6) + q] = make_int2(d, __float_as_int(w));
    } else {
        int i = (bid - EBLK) * 256 + threadIdx.x;   // [0, CTOT*KTOT)
        if (i < CTOT) bcat2[i] = (i & 1) ? bh[i >> 1] : bz[i >> 1];
        int cc = i / KTOT, k = i % KTOT;
        int gate = cc & 1, o = cc >> 1;
        const float* W = gate ? Wh : Wz;
        float v;
        if (k < 128)      v = W[(size_t)k * 128 + o] + W[(size_t)(512 + k) * 128 + o];
        else if (k < 256) v = W[(size_t)(256 + (k - 128)) * 128 + o];
        else              v = W[(size_t)(768 + (k - 256)) * 128 + o];
        WT[(size_t)cc * KTOT + k] = f2bf(v);
    }
}

// ---------------------------------------------------------------------------
// Normalize: one wave per node. Degrees via local shuffle reduce over own
// buckets (no atomics, no random gather). Writes 3 bf16 row-sets for all 4
// batches: xb16 = x (GEMM X part), xn_o = x*dinv_out (gathered by in-lists),
// xn_i = x*dinv_in (gathered by out-lists). Lane l handles cols 2l, 2l+1.
// ---------------------------------------------------------------------------
__global__ __launch_bounds__(256) void k_norm(
        const float* __restrict__ x,
        const unsigned* __restrict__ cnt_in, const unsigned* __restrict__ cnt_out,
        const int2* __restrict__ bin, const int2* __restrict__ bout,
        unsigned short* __restrict__ xb16,
        unsigned short* __restrict__ xn_o, unsigned short* __restrict__ xn_i) {
    int wv = threadIdx.x >> 6, l = threadIdx.x & 63;
    int n = blockIdx.x * 4 + wv;
    if (n >= NN) return;
    int mi = (int)min(cnt_in[n], (unsigned)CAP);
    int mo = (int)min(cnt_out[n], (unsigned)CAP);
    float wi = 0.f, wo = 0.f;
    if (l < mi) wi = __int_as_float(bin[((size_t)n << 6) + l].y);
    if (l < mo) wo = __int_as_float(bout[((size_t)n << 6) + l].y);
#pragma unroll
    for (int s = 1; s < 64; s <<= 1) {
        wi += __shfl_xor(wi, s);
        wo += __shfl_xor(wo, s);
    }
    float dio = wo > 0.f ? 1.f / wo : 0.f;   // dinv_out[n]
    float dii = wi > 0.f ? 1.f / wi : 0.f;   // dinv_in[n]
#pragma unroll
    for (int b = 0; b < BB; ++b) {
        size_t off = ((size_t)b * NN + n) * SEQ + 2 * l;
        float2 xv = *(const float2*)&x[off];
        *(unsigned*)&xb16[off] = (unsigned)f2bf(xv.x) | ((unsigned)f2bf(xv.y) << 16);
        *(unsigned*)&xn_o[off] = (unsigned)f2bf(xv.x * dio) | ((unsigned)f2bf(xv.y * dio) << 16);
        *(unsigned*)&xn_i[off] = (unsigned)f2bf(xv.x * dii) | ((unsigned)f2bf(xv.y * dii) << 16);
    }
}

// ---------------------------------------------------------------------------
// Diffusion, one wave per (node, batch, list): 40000 waves.
// XCD slot remap (R13): slot = blockIdx&7 = (batch<<1)|list, so each XCD's
// L2 random-rereads exactly ONE 2.56 MB normalized array (fits 4 MB L2;
// previously xn_o+xn_i = 5.1 MB thrashed). n = pos*4+wv directly.
// Lane l: slot h=l>>4 (row j+h), col group q=l&15 (8 bf16); one uint4 load
// = 4 rows x 128 cols. Cross-slot reduce via shfl_xor(16/32).
// ---------------------------------------------------------------------------
#define ACC8(A, v, cf) {                                              \
    A[0] += (cf) * __uint_as_float((v).x << 16);                      \
    A[1] += (cf) * __uint_as_float((v).x & 0xFFFF0000u);              \
    A[2] += (cf) * __uint_as_float((v).y << 16);                      \
    A[3] += (cf) * __uint_as_float((v).y & 0xFFFF0000u);              \
    A[4] += (cf) * __uint_as_float((v).z << 16);                      \
    A[5] += (cf) * __uint_as_float((v).z & 0xFFFF0000u);              \
    A[6] += (cf) * __uint_as_float((v).w << 16);                      \
    A[7] += (cf) * __uint_as_float((v).w & 0xFFFF0000u); }

__global__ __launch_bounds__(256) void k_diffuse(
        const unsigned short* __restrict__ xn_o, const unsigned short* __restrict__ xn_i,
        const unsigned* __restrict__ cnt_in, const unsigned* __restrict__ cnt_out,
        const int2* __restrict__ bin, const int2* __restrict__ bout,
        unsigned short* __restrict__ Inb) {
    __shared__ int2 sb[4][CAP + 4];
    int bid = blockIdx.x;                 // [0, 10000)
    int slot = bid & 7, pos = bid >> 3;   // pos in [0, 1250)
    int b = slot >> 1, list = slot & 1;   // XCD: one batch, ONE list
    int wv = threadIdx.x >> 6;
    int n = pos * 4 + wv;                 // [0, 5000)
    int l = threadIdx.x & 63;
    int h = l >> 4, q = l & 15;
    const unsigned short* xs = (list ? xn_i : xn_o) + (size_t)b * NN * SEQ;

    const int2* bkt = list ? bout : bin;
    int m = (int)min((list ? cnt_out : cnt_in)[n], (unsigned)CAP);
    if (l < m) {
        sb[wv][l] = bkt[((size_t)n << 6) + l];      // (idx, w) raw
    } else if (l < ((m + 3) & ~3)) {
        sb[wv][l] = make_int2(0, 0);                // pad: w=0 -> no contrib
    }
    int me = (m + 3) & ~3;

    float a[8] = {0.f, 0.f, 0.f, 0.f, 0.f, 0.f, 0.f, 0.f};
    int j = 0;
    for (; j + 7 < me; j += 8) {   // 2 loads in flight
        int2 e0 = sb[wv][j + h], e1 = sb[wv][j + 4 + h];
        uint4 v0 = *(const uint4*)&xs[(size_t)e0.x * SEQ + 8 * q];
        uint4 v1 = *(const uint4*)&xs[(size_t)e1.x * SEQ + 8 * q];
        float c0 = __int_as_float(e0.y), c1 = __int_as_float(e1.y);
        ACC8(a, v0, c0);
        ACC8(a, v1, c1);
    }
    for (; j < me; j += 4) {
        int2 e0 = sb[wv][j + h];
        uint4 v0 = *(const uint4*)&xs[(size_t)e0.x * SEQ + 8 * q];
        float c0 = __int_as_float(e0.y);
        ACC8(a, v0, c0);
    }

    // reduce over the 4 row-slots (lanes l, l^16, l^32, l^48)
#pragma unroll
    for (int r = 0; r < 8; ++r) {
        a[r] += __shfl_xor(a[r], 16);
        a[r] += __shfl_xor(a[r], 32);
    }

    // h==0 lanes (16 x uint4 = 256 B) store this wave's 128-col half
    if (h == 0) {
        unsigned short* rw = Inb + (size_t)(b * NN + n) * 256 + (list ? 128 : 0);
        uint4 pk;
        pk.x = (unsigned)f2bf(a[0]) | ((unsigned)f2bf(a[1]) << 16);
        pk.y = (unsigned)f2bf(a[2]) | ((unsigned)f2bf(a[3]) << 16);
        pk.z = (unsigned)f2bf(a[4]) | ((unsigned)f2bf(a[5]) << 16);
        pk.w = (unsigned)f2bf(a[6]) | ((unsigned)f2bf(a[7]) << 16);
        *(uint4*)&rw[8 * q] = pk;
    }
}

// ---------------------------------------------------------------------------
// MFMA GEMM + fused epilogue (R8-proven). 8 waves/block (512 thr), wave-tile
// 64x32 -> 2512 waves. A: k<128 from xb16 (per-lane row ptr), k>=128 from
// Inb[r][256]. 3-buffer counted-vmcnt pipeline (steady-state vmcnt(2)).
// Epilogue: even lane 1/(1+e^z)=1-sigm, odd lane tanh; shfl_xor(1) combines.
// ---------------------------------------------------------------------------
__global__ __launch_bounds__(512) void k_mm(
        const unsigned short* __restrict__ xb16,
        const unsigned short* __restrict__ Inb, const unsigned short* __restrict__ WT,
        const float* __restrict__ bcat2, float* __restrict__ out) {
    __shared__ unsigned short lA[3][4096];  // [buf][frag f*512 + lane*8]
    __shared__ unsigned short lB[3][4096];
    int t = threadIdx.x, w = t >> 6, l = t & 63;
    int lr = l & 15, lk = l >> 4;
    int n0 = blockIdx.x * 128;
    int c0 = blockIdx.y * 128;
    int wr = w >> 2, wc = w & 3;
    f32x4 acc[4][2] = {};

    // per-lane source rows for this wave's staged fragment (f == w)
    int r = n0 + w * 16 + lr;
    int bidx = (r >= 15000) ? 3 : (r >= 10000) ? 2 : (r >= 5000) ? 1 : 0;
    const unsigned short* xrow = xb16 + ((size_t)bidx * NN + (r - bidx * NN)) * SEQ;
    const unsigned short* irow = Inb + (size_t)r * 256;
    const unsigned short* wrow = WT + (size_t)(c0 + w * 16 + lr) * KTOT;

#define STAGE(buf, k0)                                                            \
    {                                                                             \
        const unsigned short* sa = ((k0) < 128) ? (xrow + (k0) + lk * 8)          \
                                                : (irow + ((k0) - 128) + lk * 8); \
        __builtin_amdgcn_global_load_lds(                                         \
            (const __attribute__((address_space(1))) void*)sa,                    \
            (__attribute__((address_space(3))) void*)&lA[buf][w * 512], 16, 0, 0);\
        const unsigned short* sb = wrow + (k0) + lk * 8;                          \
        __builtin_amdgcn_global_load_lds(                                         \
            (const __attribute__((address_space(1))) void*)sb,                    \
            (__attribute__((address_space(3))) void*)&lB[buf][w * 512], 16, 0, 0);\
    }

    STAGE(0, 0);
    STAGE(1, 32);

#pragma unroll
    for (int ks = 0; ks < 12; ++ks) {
        if (ks < 11) asm volatile("s_waitcnt vmcnt(2)" ::: "memory");
        else         asm volatile("s_waitcnt vmcnt(0)" ::: "memory");
        __builtin_amdgcn_s_barrier();
        const int bf = ks % 3;
        bf16x8 a[4], bfr[2];
#pragma unroll
        for (int i = 0; i < 4; ++i) a[i] = *(const bf16x8*)&lA[bf][(wr * 4 + i) * 512 + l * 8];
#pragma unroll
        for (int jj = 0; jj < 2; ++jj) bfr[jj] = *(const bf16x8*)&lB[bf][(wc * 2 + jj) * 512 + l * 8];
#pragma unroll
        for (int i = 0; i < 4; ++i)
#pragma unroll
            for (int jj = 0; jj < 2; ++jj)
                acc[i][jj] = __builtin_amdgcn_mfma_f32_16x16x32_bf16(a[i], bfr[jj], acc[i][jj], 0, 0, 0);
        if (ks + 2 < 12) STAGE((ks + 2) % 3, (ks + 2) * 32);
    }
#undef STAGE

    // Epilogue: row = n0+wr*64+i*16+lk*4+rr, col cc = c0+wc*32+jj*16+lr
    int row_base = n0 + wr * 64;
    bool odd = (l & 1);
#pragma unroll
    for (int jj = 0; jj < 2; ++jj) {
        int cc = c0 + wc * 32 + jj * 16 + lr;
        float bias = bcat2[cc];
        int o = cc >> 1;
#pragma unroll
        for (int i = 0; i < 4; ++i) {
#pragma unroll
            for (int rr = 0; rr < 4; ++rr) {
                float v = acc[i][jj][rr] + bias;
                // even lane (v=z_pre): u = 1/(1+e^v)    = 1 - sigmoid(v)
                // odd  lane (v=h_pre): u = 1-2/(e^2v+1) = tanh(v)
                float ex = __expf(odd ? 2.f * v : v);
                float u = odd ? (1.f - 2.f / (ex + 1.f)) : (1.f / (1.f + ex));
                float g = __shfl_xor(u, 1);
                if (!odd) {
                    int row = row_base + i * 16 + lk * 4 + rr;
                    if (row < MTOT) out[(size_t)row * OUTC + o] = u * g;
                }
            }
        }
    }
}

// ---------------------------------------------------------------------------
extern "C" void kernel_launch(void* const* d_in, const int* in_sizes, int n_in,
                              void* d_out, int out_size, void* d_ws, size_t ws_size,
                              hipStream_t stream) {
    const float* x  = (const float*)d_in[0];
    const int*   ei = (const int*)d_in[1];
    const float* ew = (const float*)d_in[2];
    const float* Wz = (const float*)d_in[3];
    const float* bz = (const float*)d_in[4];
    // d_in[5]=Wr, d_in[6]=br dead (H0==0 -> Xc2==Xc, R unused)
    const float* Wh = (const float*)d_in[7];
    const float* bh = (const float*)d_in[8];

    float* ws = (float*)d_ws;
    unsigned* cnt_in  = (unsigned*)(ws + 0);           // 5000
    unsigned* cnt_out = (unsigned*)(ws + 5000);        // 5000
    float*    bcat2   = ws + 10000;                    // 256
    unsigned short* WT = (unsigned short*)(ws + 10256);  // 256*384 bf16 (49152 fl)
    int2*     bin  = (int2*)(ws + 59408);              // 5000*64 int2 (640000 fl)
    int2*     bout = (int2*)(ws + 699408);             // 5000*64 int2 (640000 fl)
    unsigned short* xb16 = (unsigned short*)(ws + 1339408); // 2.56M bf16 (1.28M fl)
    unsigned short* xn_o = (unsigned short*)(ws + 2619408); // 2.56M bf16
    unsigned short* xn_i = (unsigned short*)(ws + 3899408); // 2.56M bf16
    unsigned short* Inb  = (unsigned short*)(ws + 5179408); // MPAD*256 bf16

    k_zero<<<10, 256, 0, stream>>>((unsigned*)ws);
    k_bucket_fold<<<EBLK + FBLK, 256, 0, stream>>>(
        ei, ew, Wz, bz, Wh, bh, cnt_in, cnt_out, bin, bout, WT, bcat2);
    k_norm<<<1250, 256, 0, stream>>>(x, cnt_in, cnt_out, bin, bout, xb16, xn_o, xn_i);
    k_diffuse<<<2 * NN, 256, 0, stream>>>(xn_o, xn_i, cnt_in, cnt_out, bin, bout, Inb);
    dim3 g(MPAD / 128, 2);
    k_mm<<<g, 512, 0, stream>>>(xb16, Inb, WT, bcat2, (float*)d_out);
}